// Round 20
// baseline (125.992 us; speedup 1.0000x reference)
//
#include <hip/hip_runtime.h>

// Fused double-softmax attention, fp32 in/out, f16 MFMA for QK^T and PV.
// B=4 H=8 S=1024 D=64. Outputs: context [B,H,S,D] then attn [B,H,S,S].
// R20 = R19 (BQ=32) + TWO k-fragments per iteration in Phases A and C:
// all loads of an iteration feed the SAME iteration's MFMAs (8 loads batched
// -> 2x per-wave MLP; serial chain halves: A 8->4 iters, C 16->8 iters).
typedef _Float16 f16;
typedef _Float16 f16x8 __attribute__((ext_vector_type(8)));
typedef _Float16 f16x4 __attribute__((ext_vector_type(4)));
typedef float f32x4 __attribute__((ext_vector_type(4)));
typedef int   i32x4 __attribute__((ext_vector_type(4)));

constexpr int B_ = 4, H_ = 8, S_ = 1024, D_ = 64;
constexpr int BQ = 32;        // q rows per block
constexpr int NT = 512;       // 8 waves
constexpr int QH_LD = 72;     // Qh row stride in f16
constexpr int SC_LD = 1032;   // sch row stride in f16
constexpr float LOG2E = 1.44269504f;

__device__ __forceinline__ float wred(float v) {
#pragma unroll
  for (int off = 32; off > 0; off >>= 1) v += __shfl_xor(v, off);
  return v;
}

#define PACK8(DST, X0, X1)                                                    \
  DST[0] = (f16)X0.x; DST[1] = (f16)X0.y; DST[2] = (f16)X0.z; DST[3] = (f16)X0.w; \
  DST[4] = (f16)X1.x; DST[5] = (f16)X1.y; DST[6] = (f16)X1.z; DST[7] = (f16)X1.w;

__global__ __launch_bounds__(NT)
void fused_attn(const float* __restrict__ Q, const float* __restrict__ K,
                const float* __restrict__ V, const int* __restrict__ mask,
                const float* __restrict__ adj, const float* __restrict__ dist,
                const float* __restrict__ cw, const float* __restrict__ cb,
                float* __restrict__ outC, float* __restrict__ outA)
{
  __shared__ __align__(16) f16 Qh[BQ * QH_LD];     // 4.6 KB
  __shared__ __align__(16) f16 sch[BQ * SC_LD];    // 66.0 KB (fscr alias later)
  __shared__ float rs1w[8][BQ];                    // 1 KB
  __shared__ float rinv2[BQ];

  const int tid = threadIdx.x;
  // bijective XCD swizzle: 1024 blocks = 8 XCDs x 128 (4 heads per XCD)
  const int sw = (blockIdx.x & 7) * 128 + (blockIdx.x >> 3);
  const int qt = sw & 31;
  const int bh = sw >> 5;
  const int q0 = qt * BQ;
  const int wv = tid >> 6;    // wave 0..7
  const int ln = tid & 63;
  const int lg = ln >> 4;     // lane group 0..3
  const int li = ln & 15;

  const float* Qp = Q + ((size_t)bh * S_ + q0) * D_;
  const float* Kp = K + (size_t)bh * S_ * D_;
  const float* Vp = V + (size_t)bh * S_ * D_;
  const size_t rb = ((size_t)bh * S_ + q0) * S_;

  // stage Q tile -> f16 (512 threads x 1 float4 = 32x64)
  {
    const int q = tid >> 4, c4 = (tid & 15) << 2;
    float4 v = *(const float4*)(Qp + q * D_ + c4);
    f16* d = &Qh[q * QH_LD + c4];
    d[0] = (f16)v.x; d[1] = (f16)v.y; d[2] = (f16)v.z; d[3] = (f16)v.w;
  }
  const float w0 = cw[0], w1 = cw[1], w2 = cw[2], bb = cb[0];
  __syncthreads();                                  // (1)

  // Q fragments for BOTH q-groups (lane li = row g*16+li, k = s*32+lg*8)
  f16x8 aq00 = *(const f16x8*)&Qh[li * QH_LD + 0 * 32 + lg * 8];
  f16x8 aq01 = *(const f16x8*)&Qh[li * QH_LD + 1 * 32 + lg * 8];
  f16x8 aq10 = *(const f16x8*)&Qh[(16 + li) * QH_LD + 0 * 32 + lg * 8];
  f16x8 aq11 = *(const f16x8*)&Qh[(16 + li) * QH_LD + 1 * 32 + lg * 8];

  // ===== Phase A: e = exp(QK^T/8); 2 k-fragments x 2 q-groups per iter =======
  const int n0 = wv * 16;
  float rs0[4] = {0.f, 0.f, 0.f, 0.f};
  float rs1[4] = {0.f, 0.f, 0.f, 0.f};
#pragma unroll
  for (int c = 0; c < 4; ++c) {
    const int kgA = c * 256 + n0 + li;
    const int kgB = kgA + 128;
    const float* KrA = Kp + (size_t)kgA * D_ + lg * 8;
    const float* KrB = Kp + (size_t)kgB * D_ + lg * 8;
    // 8 loads, all consumed by THIS iteration's MFMAs
    const float4 xa0 = *(const float4*)(KrA + 0);
    const float4 xa1 = *(const float4*)(KrA + 4);
    const float4 xa2 = *(const float4*)(KrA + 32);
    const float4 xa3 = *(const float4*)(KrA + 36);
    const float4 xb0 = *(const float4*)(KrB + 0);
    const float4 xb1 = *(const float4*)(KrB + 4);
    const float4 xb2 = *(const float4*)(KrB + 32);
    const float4 xb3 = *(const float4*)(KrB + 36);
    f16x8 bA0, bA1, bB0, bB1;
    PACK8(bA0, xa0, xa1)
    PACK8(bA1, xa2, xa3)
    PACK8(bB0, xb0, xb1)
    PACK8(bB1, xb2, xb3)
    f32x4 aA0 = {0.f, 0.f, 0.f, 0.f};
    f32x4 aA1 = {0.f, 0.f, 0.f, 0.f};
    f32x4 aB0 = {0.f, 0.f, 0.f, 0.f};
    f32x4 aB1 = {0.f, 0.f, 0.f, 0.f};
    aA0 = __builtin_amdgcn_mfma_f32_16x16x32_f16(aq00, bA0, aA0, 0, 0, 0);
    aA1 = __builtin_amdgcn_mfma_f32_16x16x32_f16(aq10, bA0, aA1, 0, 0, 0);
    aB0 = __builtin_amdgcn_mfma_f32_16x16x32_f16(aq00, bB0, aB0, 0, 0, 0);
    aB1 = __builtin_amdgcn_mfma_f32_16x16x32_f16(aq10, bB0, aB1, 0, 0, 0);
    aA0 = __builtin_amdgcn_mfma_f32_16x16x32_f16(aq01, bA1, aA0, 0, 0, 0);
    aA1 = __builtin_amdgcn_mfma_f32_16x16x32_f16(aq11, bA1, aA1, 0, 0, 0);
    aB0 = __builtin_amdgcn_mfma_f32_16x16x32_f16(aq01, bB1, aB0, 0, 0, 0);
    aB1 = __builtin_amdgcn_mfma_f32_16x16x32_f16(aq11, bB1, aB1, 0, 0, 0);
#pragma unroll
    for (int r = 0; r < 4; ++r) {            // D[m][n]: m=lg*4+r, n=li
      const int m = lg * 4 + r;
      const f16 eA0 = (f16)exp2f(aA0[r] * (0.125f * LOG2E));
      const f16 eA1 = (f16)exp2f(aA1[r] * (0.125f * LOG2E));
      const f16 eB0 = (f16)exp2f(aB0[r] * (0.125f * LOG2E));
      const f16 eB1 = (f16)exp2f(aB1[r] * (0.125f * LOG2E));
      sch[m * SC_LD + kgA] = eA0;
      sch[(16 + m) * SC_LD + kgA] = eA1;
      sch[m * SC_LD + kgB] = eB0;
      sch[(16 + m) * SC_LD + kgB] = eB1;
      rs0[r] += (float)eA0 + (float)eB0;
      rs1[r] += (float)eA1 + (float)eB1;
    }
  }
#pragma unroll
  for (int r = 0; r < 4; ++r) {              // reduce over 16 lanes per group
    rs0[r] += __shfl_xor(rs0[r], 1); rs0[r] += __shfl_xor(rs0[r], 2);
    rs0[r] += __shfl_xor(rs0[r], 4); rs0[r] += __shfl_xor(rs0[r], 8);
    rs1[r] += __shfl_xor(rs1[r], 1); rs1[r] += __shfl_xor(rs1[r], 2);
    rs1[r] += __shfl_xor(rs1[r], 4); rs1[r] += __shfl_xor(rs1[r], 8);
  }
  if (li == 0) {
#pragma unroll
    for (int r = 0; r < 4; ++r) {
      rs1w[wv][lg * 4 + r] = rs0[r];
      rs1w[wv][16 + lg * 4 + r] = rs1[r];
    }
  }
  __syncthreads();                                  // (2) sch + rs1w visible

  // ===== Phase B: mask fold + conv-softmax; wave -> rows 4wv..4wv+3 ==========
#pragma unroll
  for (int rr = 0; rr < 4; ++rr) {
    const int q = 4 * wv + rr;
    const size_t base = rb + (size_t)q * S_;
    const int k0 = ln * 4;
    // batched NONTEMPORAL loads: 12 global + 4 LDS issued before any use
    const i32x4 mv0 = __builtin_nontemporal_load((const i32x4*)(mask + base + k0 + 0));
    const i32x4 mv1 = __builtin_nontemporal_load((const i32x4*)(mask + base + k0 + 256));
    const i32x4 mv2 = __builtin_nontemporal_load((const i32x4*)(mask + base + k0 + 512));
    const i32x4 mv3 = __builtin_nontemporal_load((const i32x4*)(mask + base + k0 + 768));
    const f32x4 dv0 = __builtin_nontemporal_load((const f32x4*)(dist + base + k0 + 0));
    const f32x4 dv1 = __builtin_nontemporal_load((const f32x4*)(dist + base + k0 + 256));
    const f32x4 dv2 = __builtin_nontemporal_load((const f32x4*)(dist + base + k0 + 512));
    const f32x4 dv3 = __builtin_nontemporal_load((const f32x4*)(dist + base + k0 + 768));
    const f32x4 av0 = __builtin_nontemporal_load((const f32x4*)(adj + base + k0 + 0));
    const f32x4 av1 = __builtin_nontemporal_load((const f32x4*)(adj + base + k0 + 256));
    const f32x4 av2 = __builtin_nontemporal_load((const f32x4*)(adj + base + k0 + 512));
    const f32x4 av3 = __builtin_nontemporal_load((const f32x4*)(adj + base + k0 + 768));
    const f16x4 ef0 = *(const f16x4*)&sch[q * SC_LD + k0 + 0];
    const f16x4 ef1 = *(const f16x4*)&sch[q * SC_LD + k0 + 256];
    const f16x4 ef2 = *(const f16x4*)&sch[q * SC_LD + k0 + 512];
    const f16x4 ef3 = *(const f16x4*)&sch[q * SC_LD + k0 + 768];
    __builtin_amdgcn_sched_barrier(0);
    // denominator correction from masked entries
    float corr =
        (mv0[0] ? (float)ef0[0] : 0.f) + (mv0[1] ? (float)ef0[1] : 0.f) +
        (mv0[2] ? (float)ef0[2] : 0.f) + (mv0[3] ? (float)ef0[3] : 0.f) +
        (mv1[0] ? (float)ef1[0] : 0.f) + (mv1[1] ? (float)ef1[1] : 0.f) +
        (mv1[2] ? (float)ef1[2] : 0.f) + (mv1[3] ? (float)ef1[3] : 0.f) +
        (mv2[0] ? (float)ef2[0] : 0.f) + (mv2[1] ? (float)ef2[1] : 0.f) +
        (mv2[2] ? (float)ef2[2] : 0.f) + (mv2[3] ? (float)ef2[3] : 0.f) +
        (mv3[0] ? (float)ef3[0] : 0.f) + (mv3[1] ? (float)ef3[1] : 0.f) +
        (mv3[2] ? (float)ef3[2] : 0.f) + (mv3[3] ? (float)ef3[3] : 0.f);
    float tq = 0.f;
#pragma unroll
    for (int w = 0; w < 8; ++w) tq += rs1w[w][q];   // uniform broadcast reads
    corr = wred(corr);
    const float i1 = 1.f / (tq - corr);
    const float W0 = w0 * i1 * LOG2E, W1 = w1 * LOG2E, W2 = w2 * LOG2E;
    const float BBL = bb * LOG2E;
    f16x4 af0, af1, af2, af3;
    float s2 = 0.f;
#define CSM(AF, MV, DV, AV, EF)                                               \
    {                                                                         \
      const float t0 = fmaf(W0, (float)EF[0], fmaf(W1, DV[0], fmaf(W2, AV[0], BBL))); \
      const float t1 = fmaf(W0, (float)EF[1], fmaf(W1, DV[1], fmaf(W2, AV[1], BBL))); \
      const float t2 = fmaf(W0, (float)EF[2], fmaf(W1, DV[2], fmaf(W2, AV[2], BBL))); \
      const float t3 = fmaf(W0, (float)EF[3], fmaf(W1, DV[3], fmaf(W2, AV[3], BBL))); \
      const float a0 = MV[0] ? 0.f : exp2f(t0);                               \
      const float a1 = MV[1] ? 0.f : exp2f(t1);                               \
      const float a2 = MV[2] ? 0.f : exp2f(t2);                               \
      const float a3 = MV[3] ? 0.f : exp2f(t3);                               \
      AF[0] = (f16)a0; AF[1] = (f16)a1; AF[2] = (f16)a2; AF[3] = (f16)a3;     \
      s2 += a0 + a1 + a2 + a3;                                                \
    }
    CSM(af0, mv0, dv0, av0, ef0)
    CSM(af1, mv1, dv1, av1, ef1)
    CSM(af2, mv2, dv2, av2, ef2)
    CSM(af3, mv3, dv3, av3, ef3)
#undef CSM
    *(f16x4*)&sch[q * SC_LD + k0 + 0]   = af0;
    *(f16x4*)&sch[q * SC_LD + k0 + 256] = af1;
    *(f16x4*)&sch[q * SC_LD + k0 + 512] = af2;
    *(f16x4*)&sch[q * SC_LD + k0 + 768] = af3;
    s2 = wred(s2);
    const float i2 = 1.f / s2;
    if (ln == 0) rinv2[q] = i2;
    f32x4 o;
    o[0] = (float)af0[0] * i2; o[1] = (float)af0[1] * i2;
    o[2] = (float)af0[2] * i2; o[3] = (float)af0[3] * i2;
    __builtin_nontemporal_store(o, (f32x4*)(outA + base + k0 + 0));
    o[0] = (float)af1[0] * i2; o[1] = (float)af1[1] * i2;
    o[2] = (float)af1[2] * i2; o[3] = (float)af1[3] * i2;
    __builtin_nontemporal_store(o, (f32x4*)(outA + base + k0 + 256));
    o[0] = (float)af2[0] * i2; o[1] = (float)af2[1] * i2;
    o[2] = (float)af2[2] * i2; o[3] = (float)af2[3] * i2;
    __builtin_nontemporal_store(o, (f32x4*)(outA + base + k0 + 512));
    o[0] = (float)af3[0] * i2; o[1] = (float)af3[1] * i2;
    o[2] = (float)af3[2] * i2; o[3] = (float)af3[3] * i2;
    __builtin_nontemporal_store(o, (f32x4*)(outA + base + k0 + 768));
  }
  __syncthreads();                                  // (3) sch aw-values visible

  // ===== Phase C: 2 V-fragments x 2 q-groups per iteration ==================
  // wave wv: d-tile dt = wv&3, k-half kh = wv>>2 (k in [512kh, 512kh+512)).
  const int dt = wv & 3;
  const int kh = wv >> 2;
  const int d0 = dt * 16 + li;
  f32x4 c0 = {0.f, 0.f, 0.f, 0.f};
  f32x4 c1 = {0.f, 0.f, 0.f, 0.f};
#pragma unroll 2
  for (int t = 0; t < 8; ++t) {
    const int kb = kh * 512 + t * 64;
    const float* VcA = Vp + (size_t)(kb + lg * 8) * D_ + d0;
    const float* VcB = Vp + (size_t)(kb + 32 + lg * 8) * D_ + d0;
    f16x8 bfA, bfB;
#pragma unroll
    for (int j = 0; j < 8; ++j) {
      bfA[j] = (f16)VcA[(size_t)j * D_];
      bfB[j] = (f16)VcB[(size_t)j * D_];
    }
    f16x8 a0A = *(const f16x8*)&sch[li * SC_LD + kb + lg * 8];
    f16x8 a0B = *(const f16x8*)&sch[li * SC_LD + kb + 32 + lg * 8];
    f16x8 a1A = *(const f16x8*)&sch[(16 + li) * SC_LD + kb + lg * 8];
    f16x8 a1B = *(const f16x8*)&sch[(16 + li) * SC_LD + kb + 32 + lg * 8];
    c0 = __builtin_amdgcn_mfma_f32_16x16x32_f16(a0A, bfA, c0, 0, 0, 0);
    c1 = __builtin_amdgcn_mfma_f32_16x16x32_f16(a1A, bfA, c1, 0, 0, 0);
    c0 = __builtin_amdgcn_mfma_f32_16x16x32_f16(a0B, bfB, c0, 0, 0, 0);
    c1 = __builtin_amdgcn_mfma_f32_16x16x32_f16(a1B, bfB, c1, 0, 0, 0);
  }
  __syncthreads();                                  // (4) all sch reads done
  float* fscr = reinterpret_cast<float*>(sch);      // 16 KB scratch alias
  *(f32x4*)&fscr[(wv * 64 + ln) * 8 + 0] = c0;
  *(f32x4*)&fscr[(wv * 64 + ln) * 8 + 4] = c1;
  __syncthreads();                                  // (5)
  if (tid < 256) {                    // combine k-halves, scale, write ctx
    const int t = tid >> 6, l2 = tid & 63;          // t = d-tile
    const int g2 = l2 >> 4, n = l2 & 15;
#pragma unroll
    for (int g = 0; g < 2; ++g) {
      f32x4 p  = *(const f32x4*)&fscr[((t) * 64 + l2) * 8 + 4 * g];
      f32x4 p2 = *(const f32x4*)&fscr[((t + 4) * 64 + l2) * 8 + 4 * g];
#pragma unroll
      for (int r = 0; r < 4; ++r) {
        const int m = g * 16 + g2 * 4 + r;
        outC[((size_t)bh * S_ + q0 + m) * D_ + t * 16 + n] =
            (p[r] + p2[r]) * rinv2[m];
      }
    }
  }
}

extern "C" void kernel_launch(void* const* d_in, const int* in_sizes, int n_in,
                              void* d_out, int out_size, void* d_ws, size_t ws_size,
                              hipStream_t stream) {
  const float* Q    = (const float*)d_in[0];
  const float* K    = (const float*)d_in[1];
  const float* V    = (const float*)d_in[2];
  const int*   mask = (const int*)  d_in[3];
  const float* adj  = (const float*)d_in[4];
  const float* dist = (const float*)d_in[5];
  const float* cw   = (const float*)d_in[6];
  const float* cb   = (const float*)d_in[7];

  float* outC = (float*)d_out;                                   // [B,H,S,D]
  float* outA = outC + (size_t)B_ * H_ * S_ * D_;                // [B,H,S,S]

  fused_attn<<<dim3(B_ * H_ * (S_ / BQ)), NT, 0, stream>>>(
      Q, K, V, mask, adj, dist, cw, cb, outC, outA);
}